// Round 4
// baseline (696.577 us; speedup 1.0000x reference)
//
#include <hip/hip_runtime.h>
#include <math.h>

// Problem constants: B=2,S=1024 -> T=2048 tokens; H=1024; I=2048; E=8; TOP_K=2
#define T_TOK 2048
#define H_DIM 1024
#define I_DIM 2048
#define NEXP  8

typedef _Float16 f16x8 __attribute__((ext_vector_type(8)));
typedef _Float16 f16x4 __attribute__((ext_vector_type(4)));
typedef float    f32x4 __attribute__((ext_vector_type(4)));

// ---------------------------------------------------------------------------
// async 16B global->LDS copy. LDS dest = WAVE-UNIFORM base + lane*16.
// ---------------------------------------------------------------------------
__device__ __forceinline__ void cp16(const void* g, void* l) {
  __builtin_amdgcn_global_load_lds(
      (const __attribute__((address_space(1))) void*)g,
      (__attribute__((address_space(3))) void*)l, 16, 0, 0);
}

// ---------------------------------------------------------------------------
// load 8 consecutive fp32, convert f16, one ds_write_b128.
// ---------------------------------------------------------------------------
__device__ __forceinline__ void stage8h(const float* __restrict__ src,
                                        _Float16* dst) {
  float4 f0 = ((const float4*)src)[0];
  float4 f1 = ((const float4*)src)[1];
  f16x8 h = {(_Float16)f0.x, (_Float16)f0.y, (_Float16)f0.z, (_Float16)f0.w,
             (_Float16)f1.x, (_Float16)f1.y, (_Float16)f1.z, (_Float16)f1.w};
  *(f16x8*)dst = h;
}

// ---------------------------------------------------------------------------
// fp32 -> f16 for x. n divisible by 1024.
// ---------------------------------------------------------------------------
__global__ __launch_bounds__(256) void split_x_kernel(
    const float* __restrict__ in, _Float16* __restrict__ hi, int n) {
  int i = (blockIdx.x * 256 + threadIdx.x) * 4;
  if (i >= n) return;
  float4 v = *(const float4*)(in + i);
  f16x4 hv = {(_Float16)v.x, (_Float16)v.y, (_Float16)v.z, (_Float16)v.w};
  *(f16x4*)(hi + i) = hv;
}

// ---------------------------------------------------------------------------
// Router: logits = x @ gw^T, softmax, top-2, normalized weights. 1 wave/token.
// ---------------------------------------------------------------------------
__global__ __launch_bounds__(64) void router_kernel(
    const float* __restrict__ x, const float* __restrict__ gw,
    int* __restrict__ topIdx, float* __restrict__ topW) {
  int t = blockIdx.x;
  int lane = threadIdx.x;
  float p[NEXP];
#pragma unroll
  for (int e = 0; e < NEXP; ++e) p[e] = 0.f;
  const float* xr = x + (size_t)t * H_DIM;
  for (int h = lane; h < H_DIM; h += 64) {
    float xv = xr[h];
#pragma unroll
    for (int e = 0; e < NEXP; ++e) p[e] += xv * gw[e * H_DIM + h];
  }
#pragma unroll
  for (int e = 0; e < NEXP; ++e) {
    float v = p[e];
    for (int off = 32; off > 0; off >>= 1) v += __shfl_down(v, off);
    p[e] = v;
  }
  if (lane == 0) {
    float mx = p[0];
#pragma unroll
    for (int e = 1; e < NEXP; ++e) mx = fmaxf(mx, p[e]);
    float ex[NEXP], s = 0.f;
#pragma unroll
    for (int e = 0; e < NEXP; ++e) { ex[e] = expf(p[e] - mx); s += ex[e]; }
#pragma unroll
    for (int e = 0; e < NEXP; ++e) ex[e] /= s;
    int i0 = 0; float v0 = ex[0];
#pragma unroll
    for (int e = 1; e < NEXP; ++e) if (ex[e] > v0) { v0 = ex[e]; i0 = e; }
    int i1 = -1; float v1 = -1.f;
#pragma unroll
    for (int e = 0; e < NEXP; ++e) if (e != i0 && ex[e] > v1) { v1 = ex[e]; i1 = e; }
    float sum = fmaxf(v0 + v1, 1e-12f);
    topIdx[2 * t] = i0;  topIdx[2 * t + 1] = i1;
    topW[2 * t] = v0 / sum;  topW[2 * t + 1] = v1 / sum;
  }
}

// ---------------------------------------------------------------------------
// Fused gate+up GEMM, all experts via gridDim.z, SINGLE-TERM f16.
// inter[e][t][i] = silu(x@Wg^T) * (x@Wu^T), stored f16.
// 128x128 tile (dual output), BK=32, 4 waves 2x2, 4x4 16x16x32 frags each.
// LDS 24KB (f16 elem offsets): A[0,4096) Bg[4096,8192) Bu[8192,12288).
// A tile = 128x32 f16 = 8192 BYTES: halves at byte 0 and byte 4096 (!).
// Chunk swizzle: LDS slot s of row r holds global k-chunk s ^ ((r^(r>>2))&3).
// ---------------------------------------------------------------------------
__global__ __launch_bounds__(256, 2) void gemm_gateup(
    const _Float16* __restrict__ xHi, const float* __restrict__ gup,
    _Float16* __restrict__ intHi) {
  __shared__ _Float16 lds[12288];  // 24 KB

  const int tid = threadIdx.x;
  const int wave = tid >> 6, lane = tid & 63;
  const int rowA0 = blockIdx.x * 128;  // M tile (x fastest -> share B in cache)
  const int colB0 = blockIdx.y * 128;  // N tile within I
  const int e = blockIdx.z;

  // staging coords: thread -> row r0 (and r0+64), slot s0, global chunk g0
  const int r0 = tid >> 2;
  const int s0 = tid & 3;
  const int swr = (r0 ^ (r0 >> 2)) & 3;   // same for r0+64
  const int g0 = s0 ^ swr;

  const int wm = wave >> 1, wn = wave & 1;
  const int fr = lane & 15;
  const int quad = lane >> 4;
  const int swf = (fr ^ (fr >> 2)) & 3;
  const int fk = (quad ^ swf) * 8;        // swizzled chunk offset (f16 elems)

  f32x4 accG[4][4], accU[4][4];
#pragma unroll
  for (int i = 0; i < 4; ++i)
#pragma unroll
    for (int j = 0; j < 4; ++j) {
      accG[i][j] = (f32x4){0.f, 0.f, 0.f, 0.f};
      accU[i][j] = (f32x4){0.f, 0.f, 0.f, 0.f};
    }

  const float* gupG = gup + ((size_t)e * 2 * I_DIM + colB0) * H_DIM;
  const float* gupU = gup + ((size_t)e * 2 * I_DIM + I_DIM + colB0) * H_DIM;
  char* ldsB = (char*)lds;

  for (int k0 = 0; k0 < H_DIM; k0 += 32) {
    const int kcol = k0 + g0 * 8;
    // A (x f16) direct-to-LDS async: rows 0-63 at byte 0, rows 64-127 at 4096
    cp16(xHi + (size_t)(rowA0 + r0) * H_DIM + kcol, ldsB + wave * 1024u);
    cp16(xHi + (size_t)(rowA0 + r0 + 64) * H_DIM + kcol, ldsB + 4096u + wave * 1024u);
    // B gate/up: fp32 -> f16 convert in registers -> ds_write_b128
    const size_t bro0 = (size_t)r0 * H_DIM + kcol;
    const size_t bro1 = bro0 + (size_t)64 * H_DIM;
    const int lo0 = r0 * 32 + s0 * 8;
    const int lo1 = lo0 + 64 * 32;
    stage8h(gupG + bro0, &lds[4096 + lo0]);
    stage8h(gupG + bro1, &lds[4096 + lo1]);
    stage8h(gupU + bro0, &lds[8192 + lo0]);
    stage8h(gupU + bro1, &lds[8192 + lo1]);
    __syncthreads();

    f16x8 ah[4];
#pragma unroll
    for (int i = 0; i < 4; ++i)
      ah[i] = *(const f16x8*)&lds[(wm * 64 + i * 16 + fr) * 32 + fk];
#pragma unroll
    for (int j = 0; j < 4; ++j) {
      const int boff = (wn * 64 + j * 16 + fr) * 32 + fk;
      f16x8 bg = *(const f16x8*)&lds[4096 + boff];
      f16x8 bu = *(const f16x8*)&lds[8192 + boff];
#pragma unroll
      for (int i = 0; i < 4; ++i) {
        accG[i][j] = __builtin_amdgcn_mfma_f32_16x16x32_f16(ah[i], bg, accG[i][j], 0, 0, 0);
        accU[i][j] = __builtin_amdgcn_mfma_f32_16x16x32_f16(ah[i], bu, accU[i][j], 0, 0, 0);
      }
    }
    __syncthreads();
  }

  // epilogue: C/D layout col=lane&15, row=quad*4+reg. inter = silu(g)*u -> f16
  const int er = quad * 4;
  const int ec = lane & 15;
#pragma unroll
  for (int i = 0; i < 4; ++i)
#pragma unroll
    for (int j = 0; j < 4; ++j) {
      const int row = rowA0 + wm * 64 + i * 16 + er;
      const int col = colB0 + wn * 64 + j * 16 + ec;
#pragma unroll
      for (int r = 0; r < 4; ++r) {
        float g = accG[i][j][r], u = accU[i][j][r];
        float val = g / (1.f + __expf(-g)) * u;
        intHi[((size_t)e * T_TOK + row + r) * I_DIM + col] = (_Float16)val;
      }
    }
}

// ---------------------------------------------------------------------------
// Down GEMM, all experts, SINGLE-TERM f16. eo[e][t][h] (f16) = inter @ dwn^T.
// M=T, N=H, K=I. LDS 16KB: A elems [0,4096) B [4096,8192).
// A tile = 8192 BYTES: halves at byte 0 and byte 4096 (!).
// ---------------------------------------------------------------------------
__global__ __launch_bounds__(256, 4) void gemm_down(
    const _Float16* __restrict__ intHi, const float* __restrict__ dwn,
    _Float16* __restrict__ eo) {
  __shared__ _Float16 lds[8192];  // 16 KB

  const int tid = threadIdx.x;
  const int wave = tid >> 6, lane = tid & 63;
  const int rowA0 = blockIdx.x * 128;
  const int colB0 = blockIdx.y * 128;
  const int e = blockIdx.z;

  const int r0 = tid >> 2;
  const int s0 = tid & 3;
  const int swr = (r0 ^ (r0 >> 2)) & 3;
  const int g0 = s0 ^ swr;

  const int wm = wave >> 1, wn = wave & 1;
  const int fr = lane & 15;
  const int quad = lane >> 4;
  const int swf = (fr ^ (fr >> 2)) & 3;
  const int fk = (quad ^ swf) * 8;

  f32x4 acc[4][4];
#pragma unroll
  for (int i = 0; i < 4; ++i)
#pragma unroll
    for (int j = 0; j < 4; ++j) acc[i][j] = (f32x4){0.f, 0.f, 0.f, 0.f};

  const _Float16* aBase = intHi + (size_t)e * T_TOK * I_DIM;
  const float* bBase = dwn + ((size_t)e * H_DIM + colB0) * I_DIM;
  char* ldsB = (char*)lds;

  for (int k0 = 0; k0 < I_DIM; k0 += 32) {
    const int kcol = k0 + g0 * 8;
    cp16(aBase + (size_t)(rowA0 + r0) * I_DIM + kcol, ldsB + wave * 1024u);
    cp16(aBase + (size_t)(rowA0 + r0 + 64) * I_DIM + kcol, ldsB + 4096u + wave * 1024u);
    const size_t bro0 = (size_t)r0 * I_DIM + kcol;
    const size_t bro1 = bro0 + (size_t)64 * I_DIM;
    const int lo0 = r0 * 32 + s0 * 8;
    const int lo1 = lo0 + 64 * 32;
    stage8h(bBase + bro0, &lds[4096 + lo0]);
    stage8h(bBase + bro1, &lds[4096 + lo1]);
    __syncthreads();

    f16x8 ah[4];
#pragma unroll
    for (int i = 0; i < 4; ++i)
      ah[i] = *(const f16x8*)&lds[(wm * 64 + i * 16 + fr) * 32 + fk];
#pragma unroll
    for (int j = 0; j < 4; ++j) {
      const int boff = (wn * 64 + j * 16 + fr) * 32 + fk;
      f16x8 bh = *(const f16x8*)&lds[4096 + boff];
#pragma unroll
      for (int i = 0; i < 4; ++i)
        acc[i][j] = __builtin_amdgcn_mfma_f32_16x16x32_f16(ah[i], bh, acc[i][j], 0, 0, 0);
    }
    __syncthreads();
  }

  const int er = quad * 4;
  const int ec = lane & 15;
#pragma unroll
  for (int i = 0; i < 4; ++i)
#pragma unroll
    for (int j = 0; j < 4; ++j) {
      const int row = rowA0 + wm * 64 + i * 16 + er;
      const int col = colB0 + wn * 64 + j * 16 + ec;
#pragma unroll
      for (int r = 0; r < 4; ++r)
        eo[((size_t)e * T_TOK + row + r) * H_DIM + col] = (_Float16)acc[i][j][r];
    }
}

// ---------------------------------------------------------------------------
// Gram: gram36[p] = sum_j eo[a][j]*eo[b][j] for pairs a<=b.
// ---------------------------------------------------------------------------
__global__ __launch_bounds__(256) void gram_kernel(
    const _Float16* __restrict__ eo, float* __restrict__ gram) {
  float s[36];
#pragma unroll
  for (int p = 0; p < 36; ++p) s[p] = 0.f;
  const size_t total = (size_t)T_TOK * H_DIM;
  const size_t stride = (size_t)gridDim.x * 256;
  for (size_t j = (size_t)blockIdx.x * 256 + threadIdx.x; j < total; j += stride) {
    float v[NEXP];
#pragma unroll
    for (int e = 0; e < NEXP; ++e) v[e] = (float)eo[(size_t)e * total + j];
    int p = 0;
#pragma unroll
    for (int a = 0; a < NEXP; ++a)
#pragma unroll
      for (int b = a; b < NEXP; ++b) { s[p] += v[a] * v[b]; ++p; }
  }
#pragma unroll
  for (int p = 0; p < 36; ++p) {
    float v = s[p];
    for (int off = 32; off > 0; off >>= 1) v += __shfl_down(v, off);
    s[p] = v;
  }
  __shared__ float red[4][36];
  const int wave = threadIdx.x >> 6, lane = threadIdx.x & 63;
  if (lane == 0)
#pragma unroll
    for (int p = 0; p < 36; ++p) red[wave][p] = s[p];
  __syncthreads();
  if (threadIdx.x < 36) {
    float v = red[0][threadIdx.x] + red[1][threadIdx.x] + red[2][threadIdx.x] + red[3][threadIdx.x];
    atomicAdd(&gram[threadIdx.x], v);
  }
}

// ---------------------------------------------------------------------------
// Sim: 8x8 similarity from gram36.
// ---------------------------------------------------------------------------
__global__ __launch_bounds__(64) void sim_kernel(
    const float* __restrict__ gram, float* __restrict__ simOut) {
  const int t = threadIdx.x;
  const int e1 = t >> 3, e2 = t & 7;
  int a = e1 < e2 ? e1 : e2;
  int b = e1 < e2 ? e2 : e1;
  const float g = gram[a * 8 - a * (a - 1) / 2 + (b - a)];
  const float sq1 = gram[e1 * 8 - e1 * (e1 - 1) / 2];
  const float sq2 = gram[e2 * 8 - e2 * (e2 - 1) / 2];
  float d2 = fmaxf(sq1 + sq2 - 2.f * g, 0.f);
  float dist = (e1 == e2) ? 0.f : sqrtf(d2);
  float dmax = dist;
  for (int off = 32; off > 0; off >>= 1) dmax = fmaxf(dmax, __shfl_xor(dmax, off));
  float sim = 1.f - dist / fmaxf(dmax, 1e-12f);
  if (e1 == e2) sim = 1.f;
  simOut[t] = sim;
}

// ---------------------------------------------------------------------------
// Final: out[t] = w0*eo[i0][t] + w1*eo[i1][t]. One block per token.
// ---------------------------------------------------------------------------
__global__ __launch_bounds__(256) void final_kernel(
    const _Float16* __restrict__ eo, const int* __restrict__ topIdx,
    const float* __restrict__ topW, float* __restrict__ out) {
  const int t = blockIdx.x;
  const int c = threadIdx.x * 4;
  const int i0 = topIdx[2 * t], i1 = topIdx[2 * t + 1];
  const float w0 = topW[2 * t], w1 = topW[2 * t + 1];
  const size_t per = (size_t)T_TOK * H_DIM;
  f16x4 a = *(const f16x4*)&eo[(size_t)i0 * per + (size_t)t * H_DIM + c];
  f16x4 b = *(const f16x4*)&eo[(size_t)i1 * per + (size_t)t * H_DIM + c];
  float4 r;
  r.x = w0 * (float)a[0] + w1 * (float)b[0];
  r.y = w0 * (float)a[1] + w1 * (float)b[1];
  r.z = w0 * (float)a[2] + w1 * (float)b[2];
  r.w = w0 * (float)a[3] + w1 * (float)b[3];
  *(float4*)&out[(size_t)t * H_DIM + c] = r;
}

// ---------------------------------------------------------------------------
// Workspace layout (bytes), total ~100 MiB (known-safe):
//  xHi @0 (4 MiB) | intHi @4 MiB (64 MiB) | eo f16 @68 MiB (32 MiB)
//  topIdx @100 MiB | topW @100 MiB+16K | gram @100 MiB+32K
// ---------------------------------------------------------------------------
extern "C" void kernel_launch(void* const* d_in, const int* in_sizes, int n_in,
                              void* d_out, int out_size, void* d_ws, size_t ws_size,
                              hipStream_t stream) {
  (void)in_sizes; (void)n_in; (void)out_size; (void)ws_size;
  const float* x   = (const float*)d_in[0];  // (2,1024,1024)
  const float* gw  = (const float*)d_in[1];  // (8,1024)
  const float* gup = (const float*)d_in[2];  // (8,4096,1024)
  const float* dwn = (const float*)d_in[3];  // (8,1024,2048)
  float* out = (float*)d_out;                // final (2M) ++ sim (64)

  char* ws = (char*)d_ws;
  const size_t MB = 1u << 20;
  _Float16* xHi    = (_Float16*)(ws + 0 * MB);
  _Float16* intHi  = (_Float16*)(ws + 4 * MB);
  _Float16* eo     = (_Float16*)(ws + 68 * MB);
  int*      topIdx = (int*)(ws + 100 * MB);
  float*    topW   = (float*)(ws + 100 * MB + 16384);
  float*    gram   = (float*)(ws + 100 * MB + 32768);

  split_x_kernel<<<2048, 256, 0, stream>>>(x, xHi, T_TOK * H_DIM);
  router_kernel<<<T_TOK, 64, 0, stream>>>(x, gw, topIdx, topW);
  hipMemsetAsync(gram, 0, 36 * sizeof(float), stream);

  // gate+up fused, all experts: grid x=M tiles (fastest, shares B), y=N, z=E
  gemm_gateup<<<dim3(T_TOK / 128, I_DIM / 128, NEXP), 256, 0, stream>>>(
      xHi, gup, intHi);
  // down, all experts
  gemm_down<<<dim3(T_TOK / 128, H_DIM / 128, NEXP), 256, 0, stream>>>(
      intHi, dwn, eo);

  gram_kernel<<<2048, 256, 0, stream>>>(eo, gram);
  sim_kernel<<<1, 64, 0, stream>>>(gram, out + (size_t)T_TOK * H_DIM);
  final_kernel<<<T_TOK, 256, 0, stream>>>(eo, topIdx, topW, out);
}

// Round 5
// 677.016 us; speedup vs baseline: 1.0289x; 1.0289x over previous
//
#include <hip/hip_runtime.h>
#include <math.h>

// Problem constants: B=2,S=1024 -> T=2048 tokens; H=1024; I=2048; E=8; TOP_K=2
#define T_TOK 2048
#define H_DIM 1024
#define I_DIM 2048
#define NEXP  8

typedef _Float16 f16x8 __attribute__((ext_vector_type(8)));
typedef _Float16 f16x4 __attribute__((ext_vector_type(4)));
typedef float    f32x4 __attribute__((ext_vector_type(4)));

// ---------------------------------------------------------------------------
// async 16B global->LDS copy. LDS dest = WAVE-UNIFORM base + lane*16.
// ---------------------------------------------------------------------------
__device__ __forceinline__ void cp16(const void* g, void* l) {
  __builtin_amdgcn_global_load_lds(
      (const __attribute__((address_space(1))) void*)g,
      (__attribute__((address_space(3))) void*)l, 16, 0, 0);
}

// ---------------------------------------------------------------------------
// load 8 consecutive fp32, convert f16, one ds_write_b128.
// ---------------------------------------------------------------------------
__device__ __forceinline__ void stage8h(const float* __restrict__ src,
                                        _Float16* dst) {
  float4 f0 = ((const float4*)src)[0];
  float4 f1 = ((const float4*)src)[1];
  f16x8 h = {(_Float16)f0.x, (_Float16)f0.y, (_Float16)f0.z, (_Float16)f0.w,
             (_Float16)f1.x, (_Float16)f1.y, (_Float16)f1.z, (_Float16)f1.w};
  *(f16x8*)dst = h;
}

// ---------------------------------------------------------------------------
// fp32 -> f16 streaming convert. n divisible by 1024.
// ---------------------------------------------------------------------------
__global__ __launch_bounds__(256) void cvt_f16_kernel(
    const float* __restrict__ in, _Float16* __restrict__ hi, int n) {
  int i = (blockIdx.x * 256 + threadIdx.x) * 4;
  if (i >= n) return;
  float4 v = *(const float4*)(in + i);
  f16x4 hv = {(_Float16)v.x, (_Float16)v.y, (_Float16)v.z, (_Float16)v.w};
  *(f16x4*)(hi + i) = hv;
}

// ---------------------------------------------------------------------------
// Router: logits = x @ gw^T, softmax, top-2, normalized weights. 1 wave/token.
// ---------------------------------------------------------------------------
__global__ __launch_bounds__(64) void router_kernel(
    const float* __restrict__ x, const float* __restrict__ gw,
    int* __restrict__ topIdx, float* __restrict__ topW) {
  int t = blockIdx.x;
  int lane = threadIdx.x;
  float p[NEXP];
#pragma unroll
  for (int e = 0; e < NEXP; ++e) p[e] = 0.f;
  const float* xr = x + (size_t)t * H_DIM;
  for (int h = lane; h < H_DIM; h += 64) {
    float xv = xr[h];
#pragma unroll
    for (int e = 0; e < NEXP; ++e) p[e] += xv * gw[e * H_DIM + h];
  }
#pragma unroll
  for (int e = 0; e < NEXP; ++e) {
    float v = p[e];
    for (int off = 32; off > 0; off >>= 1) v += __shfl_down(v, off);
    p[e] = v;
  }
  if (lane == 0) {
    float mx = p[0];
#pragma unroll
    for (int e = 1; e < NEXP; ++e) mx = fmaxf(mx, p[e]);
    float ex[NEXP], s = 0.f;
#pragma unroll
    for (int e = 0; e < NEXP; ++e) { ex[e] = expf(p[e] - mx); s += ex[e]; }
#pragma unroll
    for (int e = 0; e < NEXP; ++e) ex[e] /= s;
    int i0 = 0; float v0 = ex[0];
#pragma unroll
    for (int e = 1; e < NEXP; ++e) if (ex[e] > v0) { v0 = ex[e]; i0 = e; }
    int i1 = -1; float v1 = -1.f;
#pragma unroll
    for (int e = 0; e < NEXP; ++e) if (e != i0 && ex[e] > v1) { v1 = ex[e]; i1 = e; }
    float sum = fmaxf(v0 + v1, 1e-12f);
    topIdx[2 * t] = i0;  topIdx[2 * t + 1] = i1;
    topW[2 * t] = v0 / sum;  topW[2 * t + 1] = v1 / sum;
  }
}

// ---------------------------------------------------------------------------
// Fused gate+up GEMM, all experts via gridDim.z, SINGLE-TERM f16.
// inter[e][t][i] = silu(x@Wg^T) * (x@Wu^T), stored f16.
// GRID: x = N-tile, y = M-tile, z = expert. Same-B blocks (vary M) have
// linear ids differing by 16 == 0 mod 8 -> same XCD -> B-tile L2 reuse.
// 128x128 tile, BK=32, 4 waves 2x2, 4x4 16x16x32 frags each.
// LDS 24KB (f16 elem offsets): A[0,4096) Bg[4096,8192) Bu[8192,12288).
// A tile = 128x32 f16 = 8192 BYTES: halves at byte 0 and byte 4096.
// Chunk swizzle: LDS slot s of row r holds global k-chunk s ^ ((r^(r>>2))&3).
// ---------------------------------------------------------------------------
__global__ __launch_bounds__(256, 2) void gemm_gateup(
    const _Float16* __restrict__ xHi, const float* __restrict__ gup,
    _Float16* __restrict__ intHi) {
  __shared__ _Float16 lds[12288];  // 24 KB

  const int tid = threadIdx.x;
  const int wave = tid >> 6, lane = tid & 63;
  const int rowA0 = blockIdx.y * 128;  // M tile
  const int colB0 = blockIdx.x * 128;  // N tile within I (x => B co-located per XCD)
  const int e = blockIdx.z;

  // staging coords: thread -> row r0 (and r0+64), slot s0, global chunk g0
  const int r0 = tid >> 2;
  const int s0 = tid & 3;
  const int swr = (r0 ^ (r0 >> 2)) & 3;   // same for r0+64
  const int g0 = s0 ^ swr;

  const int wm = wave >> 1, wn = wave & 1;
  const int fr = lane & 15;
  const int quad = lane >> 4;
  const int swf = (fr ^ (fr >> 2)) & 3;
  const int fk = (quad ^ swf) * 8;        // swizzled chunk offset (f16 elems)

  f32x4 accG[4][4], accU[4][4];
#pragma unroll
  for (int i = 0; i < 4; ++i)
#pragma unroll
    for (int j = 0; j < 4; ++j) {
      accG[i][j] = (f32x4){0.f, 0.f, 0.f, 0.f};
      accU[i][j] = (f32x4){0.f, 0.f, 0.f, 0.f};
    }

  const float* gupG = gup + ((size_t)e * 2 * I_DIM + colB0) * H_DIM;
  const float* gupU = gup + ((size_t)e * 2 * I_DIM + I_DIM + colB0) * H_DIM;
  char* ldsB = (char*)lds;

  for (int k0 = 0; k0 < H_DIM; k0 += 32) {
    const int kcol = k0 + g0 * 8;
    // A (x f16) direct-to-LDS async: rows 0-63 at byte 0, rows 64-127 at 4096
    cp16(xHi + (size_t)(rowA0 + r0) * H_DIM + kcol, ldsB + wave * 1024u);
    cp16(xHi + (size_t)(rowA0 + r0 + 64) * H_DIM + kcol, ldsB + 4096u + wave * 1024u);
    // B gate/up: fp32 -> f16 convert in registers -> ds_write_b128
    const size_t bro0 = (size_t)r0 * H_DIM + kcol;
    const size_t bro1 = bro0 + (size_t)64 * H_DIM;
    const int lo0 = r0 * 32 + s0 * 8;
    const int lo1 = lo0 + 64 * 32;
    stage8h(gupG + bro0, &lds[4096 + lo0]);
    stage8h(gupG + bro1, &lds[4096 + lo1]);
    stage8h(gupU + bro0, &lds[8192 + lo0]);
    stage8h(gupU + bro1, &lds[8192 + lo1]);
    __syncthreads();

    f16x8 ah[4];
#pragma unroll
    for (int i = 0; i < 4; ++i)
      ah[i] = *(const f16x8*)&lds[(wm * 64 + i * 16 + fr) * 32 + fk];
#pragma unroll
    for (int j = 0; j < 4; ++j) {
      const int boff = (wn * 64 + j * 16 + fr) * 32 + fk;
      f16x8 bg = *(const f16x8*)&lds[4096 + boff];
      f16x8 bu = *(const f16x8*)&lds[8192 + boff];
#pragma unroll
      for (int i = 0; i < 4; ++i) {
        accG[i][j] = __builtin_amdgcn_mfma_f32_16x16x32_f16(ah[i], bg, accG[i][j], 0, 0, 0);
        accU[i][j] = __builtin_amdgcn_mfma_f32_16x16x32_f16(ah[i], bu, accU[i][j], 0, 0, 0);
      }
    }
    __syncthreads();
  }

  // epilogue: C/D layout col=lane&15, row=quad*4+reg. inter = silu(g)*u -> f16
  const int er = quad * 4;
  const int ec = lane & 15;
#pragma unroll
  for (int i = 0; i < 4; ++i)
#pragma unroll
    for (int j = 0; j < 4; ++j) {
      const int row = rowA0 + wm * 64 + i * 16 + er;
      const int col = colB0 + wn * 64 + j * 16 + ec;
#pragma unroll
      for (int r = 0; r < 4; ++r) {
        float g = accG[i][j][r], u = accU[i][j][r];
        float val = g / (1.f + __expf(-g)) * u;
        intHi[((size_t)e * T_TOK + row + r) * I_DIM + col] = (_Float16)val;
      }
    }
}

// ---------------------------------------------------------------------------
// Down GEMM, all experts, SINGLE-TERM f16, all-cp16 staging (B preconverted).
// eo[e][t][h] (f16) = inter @ wd16^T.  M=T, N=H, K=I.
// GRID: x = M-tile, y = N-tile, z = expert. Same-A blocks (vary N) have ids
// differing by 16 == 0 mod 8 -> same XCD -> A-slab (intHi) L2 reuse.
// LDS 16KB bytes: A [0,8192) halves 0/4096; B [8192,16384) halves 8192/12288.
// ---------------------------------------------------------------------------
__global__ __launch_bounds__(256, 4) void gemm_down(
    const _Float16* __restrict__ intHi, const _Float16* __restrict__ wd16,
    _Float16* __restrict__ eo) {
  __shared__ _Float16 lds[8192];  // 16 KB

  const int tid = threadIdx.x;
  const int wave = tid >> 6, lane = tid & 63;
  const int rowA0 = blockIdx.x * 128;
  const int colB0 = blockIdx.y * 128;
  const int e = blockIdx.z;

  const int r0 = tid >> 2;
  const int s0 = tid & 3;
  const int swr = (r0 ^ (r0 >> 2)) & 3;
  const int g0 = s0 ^ swr;

  const int wm = wave >> 1, wn = wave & 1;
  const int fr = lane & 15;
  const int quad = lane >> 4;
  const int swf = (fr ^ (fr >> 2)) & 3;
  const int fk = (quad ^ swf) * 8;

  f32x4 acc[4][4];
#pragma unroll
  for (int i = 0; i < 4; ++i)
#pragma unroll
    for (int j = 0; j < 4; ++j) acc[i][j] = (f32x4){0.f, 0.f, 0.f, 0.f};

  const _Float16* aBase = intHi + (size_t)e * T_TOK * I_DIM;
  const _Float16* bBase = wd16 + ((size_t)e * H_DIM + colB0) * I_DIM;
  char* ldsB = (char*)lds;

  for (int k0 = 0; k0 < I_DIM; k0 += 32) {
    const int kcol = k0 + g0 * 8;
    cp16(aBase + (size_t)(rowA0 + r0) * I_DIM + kcol, ldsB + wave * 1024u);
    cp16(aBase + (size_t)(rowA0 + r0 + 64) * I_DIM + kcol, ldsB + 4096u + wave * 1024u);
    cp16(bBase + (size_t)(r0) * I_DIM + kcol, ldsB + 8192u + wave * 1024u);
    cp16(bBase + (size_t)(r0 + 64) * I_DIM + kcol, ldsB + 12288u + wave * 1024u);
    __syncthreads();

    f16x8 ah[4];
#pragma unroll
    for (int i = 0; i < 4; ++i)
      ah[i] = *(const f16x8*)&lds[(wm * 64 + i * 16 + fr) * 32 + fk];
#pragma unroll
    for (int j = 0; j < 4; ++j) {
      const int boff = (wn * 64 + j * 16 + fr) * 32 + fk;
      f16x8 bh = *(const f16x8*)&lds[4096 + boff];
#pragma unroll
      for (int i = 0; i < 4; ++i)
        acc[i][j] = __builtin_amdgcn_mfma_f32_16x16x32_f16(ah[i], bh, acc[i][j], 0, 0, 0);
    }
    __syncthreads();
  }

  const int er = quad * 4;
  const int ec = lane & 15;
#pragma unroll
  for (int i = 0; i < 4; ++i)
#pragma unroll
    for (int j = 0; j < 4; ++j) {
      const int row = rowA0 + wm * 64 + i * 16 + er;
      const int col = colB0 + wn * 64 + j * 16 + ec;
#pragma unroll
      for (int r = 0; r < 4; ++r)
        eo[((size_t)e * T_TOK + row + r) * H_DIM + col] = (_Float16)acc[i][j][r];
    }
}

// ---------------------------------------------------------------------------
// Gram: gram36[p] = sum_j eo[a][j]*eo[b][j] for pairs a<=b.
// ---------------------------------------------------------------------------
__global__ __launch_bounds__(256) void gram_kernel(
    const _Float16* __restrict__ eo, float* __restrict__ gram) {
  float s[36];
#pragma unroll
  for (int p = 0; p < 36; ++p) s[p] = 0.f;
  const size_t total = (size_t)T_TOK * H_DIM;
  const size_t stride = (size_t)gridDim.x * 256;
  for (size_t j = (size_t)blockIdx.x * 256 + threadIdx.x; j < total; j += stride) {
    float v[NEXP];
#pragma unroll
    for (int e = 0; e < NEXP; ++e) v[e] = (float)eo[(size_t)e * total + j];
    int p = 0;
#pragma unroll
    for (int a = 0; a < NEXP; ++a)
#pragma unroll
      for (int b = a; b < NEXP; ++b) { s[p] += v[a] * v[b]; ++p; }
  }
#pragma unroll
  for (int p = 0; p < 36; ++p) {
    float v = s[p];
    for (int off = 32; off > 0; off >>= 1) v += __shfl_down(v, off);
    s[p] = v;
  }
  __shared__ float red[4][36];
  const int wave = threadIdx.x >> 6, lane = threadIdx.x & 63;
  if (lane == 0)
#pragma unroll
    for (int p = 0; p < 36; ++p) red[wave][p] = s[p];
  __syncthreads();
  if (threadIdx.x < 36) {
    float v = red[0][threadIdx.x] + red[1][threadIdx.x] + red[2][threadIdx.x] + red[3][threadIdx.x];
    atomicAdd(&gram[threadIdx.x], v);
  }
}

// ---------------------------------------------------------------------------
// Sim: 8x8 similarity from gram36.
// ---------------------------------------------------------------------------
__global__ __launch_bounds__(64) void sim_kernel(
    const float* __restrict__ gram, float* __restrict__ simOut) {
  const int t = threadIdx.x;
  const int e1 = t >> 3, e2 = t & 7;
  int a = e1 < e2 ? e1 : e2;
  int b = e1 < e2 ? e2 : e1;
  const float g = gram[a * 8 - a * (a - 1) / 2 + (b - a)];
  const float sq1 = gram[e1 * 8 - e1 * (e1 - 1) / 2];
  const float sq2 = gram[e2 * 8 - e2 * (e2 - 1) / 2];
  float d2 = fmaxf(sq1 + sq2 - 2.f * g, 0.f);
  float dist = (e1 == e2) ? 0.f : sqrtf(d2);
  float dmax = dist;
  for (int off = 32; off > 0; off >>= 1) dmax = fmaxf(dmax, __shfl_xor(dmax, off));
  float sim = 1.f - dist / fmaxf(dmax, 1e-12f);
  if (e1 == e2) sim = 1.f;
  simOut[t] = sim;
}

// ---------------------------------------------------------------------------
// Final: out[t] = w0*eo[i0][t] + w1*eo[i1][t]. One block per token.
// ---------------------------------------------------------------------------
__global__ __launch_bounds__(256) void final_kernel(
    const _Float16* __restrict__ eo, const int* __restrict__ topIdx,
    const float* __restrict__ topW, float* __restrict__ out) {
  const int t = blockIdx.x;
  const int c = threadIdx.x * 4;
  const int i0 = topIdx[2 * t], i1 = topIdx[2 * t + 1];
  const float w0 = topW[2 * t], w1 = topW[2 * t + 1];
  const size_t per = (size_t)T_TOK * H_DIM;
  f16x4 a = *(const f16x4*)&eo[(size_t)i0 * per + (size_t)t * H_DIM + c];
  f16x4 b = *(const f16x4*)&eo[(size_t)i1 * per + (size_t)t * H_DIM + c];
  float4 r;
  r.x = w0 * (float)a[0] + w1 * (float)b[0];
  r.y = w0 * (float)a[1] + w1 * (float)b[1];
  r.z = w0 * (float)a[2] + w1 * (float)b[2];
  r.w = w0 * (float)a[3] + w1 * (float)b[3];
  *(float4*)&out[(size_t)t * H_DIM + c] = r;
}

// ---------------------------------------------------------------------------
// Workspace layout (bytes), total ~132 MiB:
//  xHi @0 (4 MiB) | intHi @4 MiB (64 MiB) | eo f16 @68 MiB (32 MiB)
//  wd16 @100 MiB (32 MiB) | topIdx @132 MiB | topW +16K | gram +32K
// ---------------------------------------------------------------------------
extern "C" void kernel_launch(void* const* d_in, const int* in_sizes, int n_in,
                              void* d_out, int out_size, void* d_ws, size_t ws_size,
                              hipStream_t stream) {
  (void)in_sizes; (void)n_in; (void)out_size; (void)ws_size;
  const float* x   = (const float*)d_in[0];  // (2,1024,1024)
  const float* gw  = (const float*)d_in[1];  // (8,1024)
  const float* gup = (const float*)d_in[2];  // (8,4096,1024)
  const float* dwn = (const float*)d_in[3];  // (8,1024,2048)
  float* out = (float*)d_out;                // final (2M) ++ sim (64)

  char* ws = (char*)d_ws;
  const size_t MB = 1u << 20;
  _Float16* xHi    = (_Float16*)(ws + 0 * MB);
  _Float16* intHi  = (_Float16*)(ws + 4 * MB);
  _Float16* eo     = (_Float16*)(ws + 68 * MB);
  _Float16* wd16   = (_Float16*)(ws + 100 * MB);
  int*      topIdx = (int*)(ws + 132 * MB);
  float*    topW   = (float*)(ws + 132 * MB + 16384);
  float*    gram   = (float*)(ws + 132 * MB + 32768);

  cvt_f16_kernel<<<2048, 256, 0, stream>>>(x, xHi, T_TOK * H_DIM);
  cvt_f16_kernel<<<16384, 256, 0, stream>>>(dwn, wd16, NEXP * H_DIM * I_DIM);
  router_kernel<<<T_TOK, 64, 0, stream>>>(x, gw, topIdx, topW);
  hipMemsetAsync(gram, 0, 36 * sizeof(float), stream);

  // gate+up fused: grid x=N (B-tiles XCD-co-located), y=M, z=E
  gemm_gateup<<<dim3(I_DIM / 128, T_TOK / 128, NEXP), 256, 0, stream>>>(
      xHi, gup, intHi);
  // down: grid x=M (A-slabs XCD-co-located), y=N, z=E
  gemm_down<<<dim3(T_TOK / 128, H_DIM / 128, NEXP), 256, 0, stream>>>(
      intHi, wd16, eo);

  gram_kernel<<<2048, 256, 0, stream>>>(eo, gram);
  sim_kernel<<<1, 64, 0, stream>>>(gram, out + (size_t)T_TOK * H_DIM);
  final_kernel<<<T_TOK, 256, 0, stream>>>(eo, topIdx, topW, out);
}